// Round 6
// baseline (382.746 us; speedup 1.0000x reference)
//
#include <hip/hip_runtime.h>
#include <hip/hip_fp16.h>
#include <math.h>

// ---------------------------------------------------------------------------
// SGConv (K=2) + linear + relu + linear + sigmoid.
// N = 500K nodes (dim 1), E = 16M random edges, self-loops w=1.
//
// Destination-bucketed edge partition (BSZ=8192, nb=62), all accumulation in
// LDS. Round 6: split edge streams (u32 packed idx + fp16 w -> 6 B/edge),
// 4-edge-unrolled accum (4-way gather MLP), scatter at 2 edges/thread/round.
//   h[c] = dinv[c] * ( sum_e w*g[row] + g[c] ),  g = dinv .* h_prev
// ---------------------------------------------------------------------------

#define BSH  13
#define BSZ  8192      // nodes per bucket (13 bits local + 19 bits row = 32)
#define MAXB 64        // max buckets
#define NBLK 512       // partition blocks
#define SCT  1024      // threads in count/scatter
#define PR   (2*SCT)   // edges per scatter round
#define ACT  1024      // threads in accum
#define SD   96        // staging depth per bucket (mean fill 33, 11 sigma)
#define EPAD (64*MAXB) // bucket-base padding allowance

__device__ __forceinline__ void lds_fadd(float* p, float v) {
    unsafeAtomicAdd(p, v);   // ds_add_f32
}

// ---------- partition passes ----------

__global__ void k_count(const int* __restrict__ col, int E, int chunk,
                        unsigned* __restrict__ cnt, int nb, int vec_ok) {
    __shared__ unsigned hist[MAXB];
    const int k = blockIdx.x;
    for (int i = threadIdx.x; i < nb; i += blockDim.x) hist[i] = 0;
    __syncthreads();
    const int lo = k * chunk;
    const int hi = min(E, lo + chunk);
    const int len = hi - lo;
    if (len > 0) {
        if (vec_ok) {
            const int nv = len >> 2;
            const uint4* c4 = (const uint4*)(col + lo);
            for (int i = threadIdx.x; i < nv; i += blockDim.x) {
                uint4 v = c4[i];
                atomicAdd(&hist[v.x >> BSH], 1u);
                atomicAdd(&hist[v.y >> BSH], 1u);
                atomicAdd(&hist[v.z >> BSH], 1u);
                atomicAdd(&hist[v.w >> BSH], 1u);
            }
            for (int i = lo + (nv << 2) + (int)threadIdx.x; i < hi; i += blockDim.x)
                atomicAdd(&hist[((unsigned)col[i]) >> BSH], 1u);
        } else {
            for (int i = lo + (int)threadIdx.x; i < hi; i += blockDim.x)
                atomicAdd(&hist[((unsigned)col[i]) >> BSH], 1u);
        }
    }
    __syncthreads();
    for (int i = threadIdx.x; i < nb; i += blockDim.x)
        cnt[(size_t)i * NBLK + k] = hist[i];        // bucket-major
}

// block b: exclusive scan of cnt[b][0..NBLK) -> off[b][*]; total -> gtot[b]
__global__ void k_scan_bucket(const unsigned* __restrict__ cnt,
                              unsigned* __restrict__ off,
                              unsigned* __restrict__ gtot) {
    __shared__ unsigned sc[128];
    const int b = blockIdx.x, t = threadIdx.x;      // 128 threads, NBLK=512
    const uint4* src = (const uint4*)(cnt + (size_t)b * NBLK);
    uint4 v = src[t];
    unsigned s = v.x + v.y + v.z + v.w;
    sc[t] = s; __syncthreads();
    #pragma unroll
    for (int d = 1; d < 128; d <<= 1) {
        unsigned a = (t >= d) ? sc[t - d] : 0;
        __syncthreads();
        sc[t] += a;
        __syncthreads();
    }
    unsigned run = sc[t] - s;                       // exclusive prefix
    uint4 o;
    o.x = run; run += v.x;
    o.y = run; run += v.y;
    o.z = run; run += v.z;
    o.w = run;
    ((uint4*)(off + (size_t)b * NBLK))[t] = o;
    if (t == 127) gtot[b] = sc[127];
}

// bucket bases padded to multiples of 64 edges (alignment for vector loads)
__global__ void k_scan_base(const unsigned* __restrict__ gtot,
                            unsigned* __restrict__ bstart, int nb) {
    __shared__ unsigned sc[64];
    const int t = threadIdx.x;                      // 64 threads
    unsigned s = (t < nb) ? ((gtot[t] + 63u) & ~63u) : 0;
    sc[t] = s; __syncthreads();
    #pragma unroll
    for (int d = 1; d < 64; d <<= 1) {
        unsigned a = (t >= d) ? sc[t - d] : 0;
        __syncthreads();
        sc[t] += a;
        __syncthreads();
    }
    if (t < nb) bstart[t] = sc[t] - s;
    if (t == 0) bstart[nb] = sc[63];
}

// LDS-staged scatter into split streams (idx u32, w fp16).
__global__ __launch_bounds__(SCT, 2)
void k_scatter(const int* __restrict__ row, const int* __restrict__ col,
               const float* __restrict__ w, int E, int chunk,
               const unsigned* __restrict__ off,
               const unsigned* __restrict__ bstart, int nb,
               unsigned* __restrict__ idxs, unsigned short* __restrict__ w16,
               int vec_ok) {
    __shared__ unsigned       sidx[MAXB][SD];
    __shared__ unsigned short sw[MAXB][SD];
    __shared__ unsigned       fill[MAXB];
    __shared__ unsigned       gbase[MAXB];
    const int k = blockIdx.x;
    const int tid = threadIdx.x;
    for (int i = tid; i < nb; i += blockDim.x) {
        fill[i]  = 0;
        gbase[i] = bstart[i] + off[(size_t)i * NBLK + k];
    }
    __syncthreads();
    const int lo = k * chunk;
    const int hi = min(E, lo + chunk);
    const int wv = tid >> 6, ln = tid & 63;
    const int nwv = SCT >> 6;
    for (int base = lo; base < hi; base += PR) {
        const int i0 = base + tid * 2;
        unsigned c0 = 0, c1 = 0, r0 = 0, r1 = 0;
        float w0 = 0.f, w1 = 0.f;
        int have = 0;
        if (i0 + 1 < hi) {
            if (vec_ok) {
                uint2 c2 = *(const uint2*)(col + i0);
                uint2 r2 = *(const uint2*)(row + i0);
                float2 w2 = *(const float2*)(w + i0);
                c0 = c2.x; c1 = c2.y; r0 = r2.x; r1 = r2.y; w0 = w2.x; w1 = w2.y;
            } else {
                c0 = (unsigned)col[i0];   c1 = (unsigned)col[i0+1];
                r0 = (unsigned)row[i0];   r1 = (unsigned)row[i0+1];
                w0 = w[i0];               w1 = w[i0+1];
            }
            have = 2;
        } else if (i0 < hi) {
            c0 = (unsigned)col[i0]; r0 = (unsigned)row[i0]; w0 = w[i0];
            have = 1;
        }
        if (have >= 1) {
            unsigned b = c0 >> BSH;
            unsigned pk = (c0 & (BSZ - 1)) | (r0 << BSH);
            unsigned short ww = __half_as_ushort(__float2half(w0));
            unsigned p = atomicAdd(&fill[b], 1u);
            if (p < SD) { sidx[b][p] = pk; sw[b][p] = ww; }
            else { unsigned gp = gbase[b] + p; idxs[gp] = pk; w16[gp] = ww; }
        }
        if (have == 2) {
            unsigned b = c1 >> BSH;
            unsigned pk = (c1 & (BSZ - 1)) | (r1 << BSH);
            unsigned short ww = __half_as_ushort(__float2half(w1));
            unsigned p = atomicAdd(&fill[b], 1u);
            if (p < SD) { sidx[b][p] = pk; sw[b][p] = ww; }
            else { unsigned gp = gbase[b] + p; idxs[gp] = pk; w16[gp] = ww; }
        }
        __syncthreads();
        // flush: wave wv owns buckets wv, wv+nwv, ...
        for (int b = wv; b < nb; b += nwv) {
            unsigned nf  = fill[b];
            unsigned nfl = nf < SD ? nf : SD;
            unsigned gb  = gbase[b];
            if ((unsigned)ln < nfl) { idxs[gb + ln] = sidx[b][ln]; w16[gb + ln] = sw[b][ln]; }
            unsigned l2 = 64u + ln;
            if (l2 < nfl)           { idxs[gb + l2] = sidx[b][l2]; w16[gb + l2] = sw[b][l2]; }
            if (ln == 0) { gbase[b] = gb + nf; fill[b] = 0; }
        }
        __syncthreads();
    }
}

// ---------- bucketed accumulation (LDS atomics, S sub-blocks/bucket) ----------

template <bool GATHER>
__global__ __launch_bounds__(ACT, 2)
void k_accum(const unsigned* __restrict__ idxs,
             const unsigned short* __restrict__ w16,
             const unsigned* __restrict__ bstart,
             const unsigned* __restrict__ gtot,
             const float* __restrict__ gin,
             float* __restrict__ partials, int S, int nb) {
    __shared__ float acc[BSZ];
    const int bid = blockIdx.x;
    const int b = bid / S, s = bid - b * S;
    const int tid = threadIdx.x;
    for (int i = tid; i < BSZ; i += blockDim.x) acc[i] = 0.f;
    __syncthreads();
    const unsigned lo  = bstart[b];
    const unsigned len = gtot[b];
    unsigned s0 = (unsigned)(((unsigned long long)len * s) / S);
    unsigned s1 = (unsigned)(((unsigned long long)len * (s + 1)) / S);
    s0 = (s0 + 3u) & ~3u; if (s0 > len) s0 = len;
    if (s != S - 1) { s1 = (s1 + 3u) & ~3u; if (s1 > len) s1 = len; }
    const unsigned start = lo + s0, end = lo + s1;
    const unsigned nv = (end - start) >> 2;
    const uint4* i4 = (const uint4*)(idxs + start);
    const uint2* h4 = (const uint2*)(w16 + start);      // 4 halfs per uint2
    for (unsigned i = tid; i < nv; i += blockDim.x) {
        uint4 v  = i4[i];
        uint2 hh = h4[i];
        float f0 = __half2float(__ushort_as_half((unsigned short)(hh.x & 0xFFFFu)));
        float f1 = __half2float(__ushort_as_half((unsigned short)(hh.x >> 16)));
        float f2 = __half2float(__ushort_as_half((unsigned short)(hh.y & 0xFFFFu)));
        float f3 = __half2float(__ushort_as_half((unsigned short)(hh.y >> 16)));
        if (GATHER) {
            f0 *= gin[v.x >> BSH];
            f1 *= gin[v.y >> BSH];
            f2 *= gin[v.z >> BSH];
            f3 *= gin[v.w >> BSH];
        }
        lds_fadd(&acc[v.x & (BSZ - 1)], f0);
        lds_fadd(&acc[v.y & (BSZ - 1)], f1);
        lds_fadd(&acc[v.z & (BSZ - 1)], f2);
        lds_fadd(&acc[v.w & (BSZ - 1)], f3);
    }
    // scalar tail (last sub-block only, <=3 edges)
    for (unsigned i = start + (nv << 2) + tid; i < end; i += blockDim.x) {
        unsigned v = idxs[i];
        float f = __half2float(__ushort_as_half(w16[i]));
        if (GATHER) f *= gin[v >> BSH];
        lds_fadd(&acc[v & (BSZ - 1)], f);
    }
    __syncthreads();
    float4* p4 = (float4*)(partials + ((size_t)s * nb + b) * BSZ);
    const float4* a4 = (const float4*)acc;
    for (int i = tid; i < BSZ / 4; i += blockDim.x) p4[i] = a4[i];
}

// mode 0: dinv = rsqrt(1+sum); g = dinv*x
// mode 1: g = dinv^2 * (sum + g)          (in place)
// mode 2: out = sigmoid(lin2(relu(lin1(dinv*(sum+g)))))
__global__ void k_finish(int mode, const float* __restrict__ partials,
                         int S, int nb, int N,
                         const float* __restrict__ x,
                         float* __restrict__ dinv, float* __restrict__ g,
                         float* __restrict__ out,
                         const float* __restrict__ cw, const float* __restrict__ cb,
                         const float* __restrict__ lw, const float* __restrict__ lb) {
    const int n = blockIdx.x * blockDim.x + threadIdx.x;
    if (n >= N) return;
    const int b = n >> BSH, i = n & (BSZ - 1);
    float ssum = 0.f;
    for (int s = 0; s < S; ++s)
        ssum += partials[((size_t)s * nb + b) * BSZ + i];
    if (mode == 0) {
        float di = rsqrtf(1.0f + ssum);             // deg >= 1 (self loop)
        dinv[n] = di;
        g[n] = di * x[n];
    } else if (mode == 1) {
        float di = dinv[n];
        g[n] = di * di * (ssum + g[n]);
    } else {
        float di = dinv[n];
        float h2 = di * (ssum + g[n]);
        float t = fmaxf(h2 * cw[0] + cb[0], 0.f);
        t = t * lw[0] + lb[0];
        out[n] = 1.f / (1.f + expf(-t));
    }
}

// ---------- fallback (round-1 proven atomic path) ----------

__global__ void k_init_deg(float* __restrict__ deg, int N) {
    int i = blockIdx.x * blockDim.x + threadIdx.x;
    if (i < N) deg[i] = 1.0f;
}
__global__ void k_scatter_deg(const int* __restrict__ col, const float* __restrict__ w,
                              float* __restrict__ deg, int E) {
    int stride = gridDim.x * blockDim.x;
    for (int e = blockIdx.x * blockDim.x + threadIdx.x; e < E; e += stride)
        atomicAdd(&deg[col[e]], w[e]);
}
__global__ void k_dinv_self(const float* __restrict__ x, float* __restrict__ deg_io,
                            float* __restrict__ h1, int N) {
    int i = blockIdx.x * blockDim.x + threadIdx.x;
    if (i >= N) return;
    float d = deg_io[i];
    float di = d > 0.0f ? rsqrtf(d) : 0.0f;
    deg_io[i] = di;
    h1[i] = di * di * x[i];
}
__global__ void k_self_seed(const float* __restrict__ src, const float* __restrict__ dinv,
                            float* __restrict__ dst, int N) {
    int i = blockIdx.x * blockDim.x + threadIdx.x;
    if (i >= N) return;
    float di = dinv[i];
    dst[i] = di * di * src[i];
}
__global__ void k_hop(const int* __restrict__ row, const int* __restrict__ col,
                      const float* __restrict__ w, const float* __restrict__ dinv,
                      const float* __restrict__ src, float* __restrict__ dst, int E) {
    int stride = gridDim.x * blockDim.x;
    for (int e = blockIdx.x * blockDim.x + threadIdx.x; e < E; e += stride) {
        int r = row[e], c = col[e];
        atomicAdd(&dst[c], dinv[r] * w[e] * dinv[c] * src[r]);
    }
}
__global__ void k_epilogue(float* __restrict__ io, const float* __restrict__ cw,
                           const float* __restrict__ cb, const float* __restrict__ lw,
                           const float* __restrict__ lb, int N) {
    int i = blockIdx.x * blockDim.x + threadIdx.x;
    if (i >= N) return;
    float h = fmaxf(io[i] * cw[0] + cb[0], 0.0f);
    h = h * lw[0] + lb[0];
    io[i] = 1.0f / (1.0f + expf(-h));
}

// ---------------------------------------------------------------------------

extern "C" void kernel_launch(void* const* d_in, const int* in_sizes, int n_in,
                              void* d_out, int out_size, void* d_ws, size_t ws_size,
                              hipStream_t stream) {
    const float* x  = (const float*)d_in[0];
    const int*   ei = (const int*)d_in[1];   // (2,E)
    const float* w  = (const float*)d_in[2];
    const float* cw = (const float*)d_in[3];
    const float* cb = (const float*)d_in[4];
    const float* lw = (const float*)d_in[5];
    const float* lb = (const float*)d_in[6];

    const int N = in_sizes[0];
    const int E = in_sizes[2];
    const int* row = ei;
    const int* col = ei + E;
    float* out = (float*)d_out;

    const int nb = (N + BSZ - 1) >> BSH;
    const size_t EC = (size_t)E + EPAD;     // padded edge capacity

    // --- choose config: S in {8,4,2,1}, first that fits ws; row needs 19 bits ---
    int S = 0;
    size_t o_bstart = 0, o_gtot = 0, o_dinv = 0, o_g = 0, o_R = 0, o_idx = 0, o_w16 = 0;
    if (N <= (1 << 19) && nb >= 1 && nb <= MAXB) {
        for (int St : {8, 4, 2, 1}) {
            size_t o = 0;
            auto alloc = [&](size_t bytes) {
                o = (o + 255) & ~(size_t)255;
                size_t r = o; o += bytes; return r;
            };
            size_t b0 = alloc((size_t)(nb + 1) * 4);        // bstart
            size_t b1 = alloc((size_t)MAXB * 4);            // gtot
            size_t b2 = alloc((size_t)N * 4);               // dinv
            size_t b3 = alloc((size_t)N * 4);               // g
            size_t cntoff = 2 * (size_t)NBLK * nb * 4;      // cnt + off
            size_t parts  = (size_t)St * nb * BSZ * 4;      // partials (aliased)
            size_t b4 = alloc(cntoff > parts ? cntoff : parts);
            size_t b5 = alloc(EC * 4);                      // idx stream
            size_t b6 = alloc(EC * 2);                      // w16 stream
            if (o <= ws_size) {
                S = St; o_bstart = b0; o_gtot = b1; o_dinv = b2;
                o_g = b3; o_R = b4; o_idx = b5; o_w16 = b6;
                break;
            }
        }
    }

    if (!S) {
        // ---- fallback: proven atomic path (needs 2N floats) ----
        float* dinv = (float*)d_ws;
        float* h1   = dinv + N;
        const int BT = 256;
        const int nbn = (N + BT - 1) / BT;
        int eb = (E + BT - 1) / BT; if (eb > 2048) eb = 2048;
        k_init_deg<<<nbn, BT, 0, stream>>>(dinv, N);
        k_scatter_deg<<<eb, BT, 0, stream>>>(col, w, dinv, E);
        k_dinv_self<<<nbn, BT, 0, stream>>>(x, dinv, h1, N);
        k_hop<<<eb, BT, 0, stream>>>(row, col, w, dinv, x, h1, E);
        k_self_seed<<<nbn, BT, 0, stream>>>(h1, dinv, out, N);
        k_hop<<<eb, BT, 0, stream>>>(row, col, w, dinv, h1, out, E);
        k_epilogue<<<nbn, BT, 0, stream>>>(out, cw, cb, lw, lb, N);
        return;
    }

    char* ws = (char*)d_ws;
    unsigned*       bstart   = (unsigned*)(ws + o_bstart);
    unsigned*       gtot     = (unsigned*)(ws + o_gtot);
    float*          dinv     = (float*)(ws + o_dinv);
    float*          g        = (float*)(ws + o_g);
    unsigned*       cnt      = (unsigned*)(ws + o_R);
    unsigned*       off      = cnt + (size_t)NBLK * nb;
    float*          partials = (float*)(ws + o_R);   // aliases cnt/off
    unsigned*       idxs     = (unsigned*)(ws + o_idx);
    unsigned short* w16      = (unsigned short*)(ws + o_w16);

    int chunk = (E + NBLK - 1) / NBLK;
    chunk = (chunk + PR - 1) & ~(PR - 1);            // multiple of PR (and 4)
    const int vec4_ok =
        ((((uintptr_t)col | (uintptr_t)row | (uintptr_t)w) & 15) == 0);
    const int vec2_ok =
        ((((uintptr_t)col | (uintptr_t)row | (uintptr_t)w) & 7) == 0);

    // partition
    k_count      <<<NBLK, SCT, 0, stream>>>(col, E, chunk, cnt, nb, vec4_ok);
    k_scan_bucket<<<nb,   128, 0, stream>>>(cnt, off, gtot);
    k_scan_base  <<<1,     64, 0, stream>>>(gtot, bstart, nb);
    k_scatter    <<<NBLK, SCT, 0, stream>>>(row, col, w, E, chunk, off, bstart, nb,
                                            idxs, w16, vec2_ok);

    // accumulation passes
    const int fgrid = (N + 255) / 256;

    k_accum<false><<<nb * S, ACT, 0, stream>>>(idxs, w16, bstart, gtot,
                                               (const float*)nullptr, partials, S, nb);
    k_finish<<<fgrid, 256, 0, stream>>>(0, partials, S, nb, N, x, dinv, g, out,
                                        cw, cb, lw, lb);

    k_accum<true><<<nb * S, ACT, 0, stream>>>(idxs, w16, bstart, gtot, g,
                                              partials, S, nb);
    k_finish<<<fgrid, 256, 0, stream>>>(1, partials, S, nb, N, x, dinv, g, out,
                                        cw, cb, lw, lb);

    k_accum<true><<<nb * S, ACT, 0, stream>>>(idxs, w16, bstart, gtot, g,
                                              partials, S, nb);
    k_finish<<<fgrid, 256, 0, stream>>>(2, partials, S, nb, N, x, dinv, g, out,
                                        cw, cb, lw, lb);
}